// Round 8
// baseline (112.916 us; speedup 1.0000x reference)
//
#include <hip/hip_runtime.h>

#define NMS_NUM_CLASSES 16
#define NMS_N 2048
#define NMS_IOU_TH 0.5f
#define NMS_SCORE_TH 0.05f
#define NMS_MAX_DET 100
#define NMS_MAX_PER_CLASS 100
#define NMS_NS (NMS_NUM_CLASSES * NMS_MAX_PER_CLASS)   // 1600
#define NMS_TILE 192                 // 3 cols/lane; P(M>192) ~ 1e-10

// SESSION PITFALLS (r1-r27):
//  * float4 casts on __shared__ float -> ds_read_b128 misalignment fault.
//  * u64 LDS arrays / LDS pointer casts correlated with container deaths.
//    ONLY declared __shared__ float/uint/uchar arrays, scalar access.
//  * Serial NMS chains cost 45-65 us at M~122 -> Jacobi fixpoint (r15).
//  * Fusion via grid.sync REGRESSED (+5us); last-block fusion is different
//    (no co-residency requirement).
//  * r20: barrier removal at 16 waves: NO change. r21/r22: wave-count law,
//    16 waves best. r24: full-M chains regress; r25: chain 16 vs 32 null.
//  * r26: TILE=192 single-tile for max-M blocks: 95.7 -> 76.4 (k1 ~38->~19).
//    Duration = MAX over blocks; the Binomial tail block ran a 2nd tile.
//  * r27 (this round): (a) k2 -> 16-way sorted-list merge via binary
//    searches (per-class lists are sorted desc + -1 pads; rank = i + sum
//    of count_gt + ties(c'<c) -- exact r12 comparator over class blocks);
//    (b) fused into k1 via last-block-done (threadfence + device atomicAdd
//    on per-image counter zeroed by captured hipMemsetAsync). If absmax
//    flickers: revert to 2 dispatches, keep binsearch k2.

__device__ __forceinline__ int nms_cmp(float sj, int ij, float sq, int iq) {
    // EXACT r12 comparator semantics, bitwise (no short-circuit branches)
    return ((int)(sj > sq)) | (((int)(sj == sq)) & ((int)(ij < iq)));
}

// ---------------------------------------------------------------------------
// Fused kernel: one block per (image, class), 1024 threads (16 waves).
// Per-class NMS -> ws; last block of each image merges to out.
// ---------------------------------------------------------------------------
__global__ __launch_bounds__(1024) void nms_fused_kernel(
    const float* __restrict__ pred,   // [B, N, 6] x1,y1,x2,y2,cls,score
    float* __restrict__ ws_scores,    // [B, 1600]
    float* __restrict__ ws_boxes,     // [B, 1600, 4]
    int* __restrict__ ws_count,       // [B] arrival counters (pre-zeroed)
    float* __restrict__ out,          // [B*600] rows + [B] nvalid
    int B)
{
    const int b = blockIdx.x / NMS_NUM_CLASSES;
    const int c = blockIdx.x % NMS_NUM_CLASSES;
    const float* p = pred + (size_t)b * NMS_N * 6;
    const int tid = threadIdx.x;
    const int lane = tid & 63;
    const int w = tid >> 6;                  // wave id 0..15

    __shared__ float s_scu[NMS_N];           // unsorted scores / merge stage
    __shared__ int   s_ixu[NMS_N];           // unsorted original indices
    __shared__ float s_bxu[NMS_N * 4];       // unsorted boxes
    __shared__ int   s_rk[NMS_N];            // rank accumulators / merge ranks
    __shared__ float s_sc[NMS_N];            // sorted scores
    __shared__ float s_bx[NMS_N * 4];        // sorted boxes
    __shared__ unsigned char s_keep[NMS_N];
    __shared__ unsigned int s_supc[6 * NMS_TILE];  // [window32][col] u32 masks
    __shared__ int s_m;
    __shared__ int s_last;

    if (tid == 0) s_m = 0;
    __syncthreads();

    // ---- compact: wave-aggregated (r20/r23-proven), s_rk zero fused ----
    const float2* p2 = (const float2*)p;     // row i = p2[3i], p2[3i+1], p2[3i+2]
    for (int i = tid; i < NMS_N; i += 1024) { // uniform trips
        s_rk[i] = 0;
        float2 v0 = p2[i * 3 + 0];           // x1, y1
        float2 v1 = p2[i * 3 + 1];           // x2, y2
        float2 v2 = p2[i * 3 + 2];           // cls, score
        const bool ok = ((int)v2.x == c) && (v2.y > NMS_SCORE_TH);
        unsigned long long mask = __ballot(ok);
        int base = 0;
        if (lane == 0) {
            int cnt = __popcll(mask);
            if (cnt) base = atomicAdd(&s_m, cnt);
        }
        base = __shfl(base, 0, 64);
        if (ok) {
            int pos = base + __popcll(mask & ((1ull << lane) - 1ull));
            s_scu[pos] = v2.y;
            s_ixu[pos] = i;
            s_bxu[pos * 4 + 0] = v0.x;
            s_bxu[pos * 4 + 1] = v0.y;
            s_bxu[pos * 4 + 2] = v1.x;
            s_bxu[pos * 4 + 3] = v1.y;
        }
    }
    __syncthreads();
    const int M = s_m;

    // ---- rank: (q, 32-chunk) tasks (r23-proven), branchless 4x-unrolled ----
    {
        const int nch = (M + 31) >> 5;
        const int ntask = M * nch;
        for (int task = tid; task < ntask; task += 1024) {
            const int q = task % M;          // consecutive tids -> distinct q
            const int ch = task / M;
            const float sq = s_scu[q];
            const int   iq = s_ixu[q];
            const int j0 = ch << 5;
            int jend = j0 + 32; if (jend > M) jend = M;
            int r0 = 0, r1 = 0, r2 = 0, r3 = 0;
            int j = j0;
            for (; j + 4 <= jend; j += 4) {
                float sa = s_scu[j + 0], sb = s_scu[j + 1];
                float sc2 = s_scu[j + 2], sd = s_scu[j + 3];
                int ia = s_ixu[j + 0], ib = s_ixu[j + 1];
                int ic = s_ixu[j + 2], id = s_ixu[j + 3];
                r0 += nms_cmp(sa, ia, sq, iq);
                r1 += nms_cmp(sb, ib, sq, iq);
                r2 += nms_cmp(sc2, ic, sq, iq);
                r3 += nms_cmp(sd, id, sq, iq);
            }
            for (; j < jend; ++j)
                r0 += nms_cmp(s_scu[j], s_ixu[j], sq, iq);
            const int rk = (r0 + r1) + (r2 + r3);
            if (rk) atomicAdd(&s_rk[q], rk);
        }
    }
    __syncthreads();
    for (int q = tid; q < M; q += 1024) {
        int rk = s_rk[q];
        s_sc[rk] = s_scu[q];
        s_bx[rk * 4 + 0] = s_bxu[q * 4 + 0];
        s_bx[rk * 4 + 1] = s_bxu[q * 4 + 1];
        s_bx[rk * 4 + 2] = s_bxu[q * 4 + 2];
        s_bx[rk * 4 + 3] = s_bxu[q * 4 + 3];
        s_keep[rk] = 1;
    }
    __syncthreads();

    // ---- tiled NMS (one tile for all realistic M; loop = M>192 fallback) ----
    for (int t0 = 0; t0 < M; t0 += NMS_TILE) {
        const int tm = (M - t0 < NMS_TILE) ? (M - t0) : NMS_TILE;

        // A0 fallback: never executes for M <= 192 (the benched regime).
        if (t0 > 0) {
            for (int jj = tid; jj < tm; jj += 1024) {
                const int gj = t0 + jj;
                float jx1 = s_bx[gj * 4 + 0], jy1 = s_bx[gj * 4 + 1];
                float jx2 = s_bx[gj * 4 + 2], jy2 = s_bx[gj * 4 + 3];
                float aj = (jy2 - jy1) * (jx2 - jx1);
                int dead = 0;
                for (int i = 0; i < t0 && !dead; ++i) {
                    if (!s_keep[i]) continue;
                    float ix1 = s_bx[i * 4 + 0], iy1 = s_bx[i * 4 + 1];
                    float ix2 = s_bx[i * 4 + 2], iy2 = s_bx[i * 4 + 3];
                    float ai = (iy2 - iy1) * (ix2 - ix1);
                    float ih = fminf(iy2, jy2) - fmaxf(iy1, jy1);
                    ih = fmaxf(ih, 0.0f);
                    float iw = fminf(ix2, jx2) - fmaxf(ix1, jx1);
                    iw = fmaxf(iw, 0.0f);
                    float inter = ih * iw;
                    float uni = ai + aj - inter;
                    float iou = (inter > 0.0f) ? inter / fmaxf(uni, 1e-08f) : 0.0f;
                    dead = iou > NMS_IOU_TH;
                }
                if (dead) s_keep[gj] = 0;
            }
            __syncthreads();
        }

        // supc: (wi, j) tasks over SIX 32-row windows; u32 masks.
        for (int idx = tid; idx < 6 * tm; idx += 1024) {
            const int wi = idx / tm;
            const int jj = idx % tm;
            const int ibase = wi << 5;
            unsigned int m0 = 0, m1 = 0, m2 = 0, m3 = 0;
            int iend = jj - ibase;           // only i < j
            if (iend > 32) iend = 32;
            if (iend > 0) {
                const int gj = t0 + jj;
                float jx1 = s_bx[gj * 4 + 0], jy1 = s_bx[gj * 4 + 1];
                float jx2 = s_bx[gj * 4 + 2], jy2 = s_bx[gj * 4 + 3];
                float aj = (jy2 - jy1) * (jx2 - jx1);
                int bb = 0;
                for (; bb + 4 <= iend; bb += 4) {
#define NMS_SUP1(K, MK)                                                        \
                    {                                                          \
                        const int gi = t0 + ibase + bb + (K);                  \
                        float ix1 = s_bx[gi * 4 + 0], iy1 = s_bx[gi * 4 + 1];  \
                        float ix2 = s_bx[gi * 4 + 2], iy2 = s_bx[gi * 4 + 3];  \
                        float ai = (iy2 - iy1) * (ix2 - ix1);                  \
                        float ih = fminf(iy2, jy2) - fmaxf(iy1, jy1);          \
                        ih = fmaxf(ih, 0.0f);                                  \
                        float iw = fminf(ix2, jx2) - fmaxf(ix1, jx1);          \
                        iw = fmaxf(iw, 0.0f);                                  \
                        float inter = ih * iw;                                 \
                        float uni = ai + aj - inter;                           \
                        float iou = (inter > 0.0f) ? inter / fmaxf(uni, 1e-08f) : 0.0f; \
                        MK |= (iou > NMS_IOU_TH) ? (1u << (bb + (K))) : 0u;    \
                    }
                    NMS_SUP1(0, m0)
                    NMS_SUP1(1, m1)
                    NMS_SUP1(2, m2)
                    NMS_SUP1(3, m3)
                }
                for (; bb < iend; ++bb) {
                    const int gi = t0 + ibase + bb;
                    float ix1 = s_bx[gi * 4 + 0], iy1 = s_bx[gi * 4 + 1];
                    float ix2 = s_bx[gi * 4 + 2], iy2 = s_bx[gi * 4 + 3];
                    float ai = (iy2 - iy1) * (ix2 - ix1);
                    float ih = fminf(iy2, jy2) - fmaxf(iy1, jy1);
                    ih = fmaxf(ih, 0.0f);
                    float iw = fminf(ix2, jx2) - fmaxf(ix1, jx1);
                    iw = fmaxf(iw, 0.0f);
                    float inter = ih * iw;
                    float uni = ai + aj - inter;
                    float iou = (inter > 0.0f) ? inter / fmaxf(uni, 1e-08f) : 0.0f;
                    m0 |= (iou > NMS_IOU_TH) ? (1u << bb) : 0u;
                }
#undef NMS_SUP1
            }
            s_supc[wi * NMS_TILE + jj] = (m0 | m1) | (m2 | m3);
        }
        __syncthreads();                     // supc complete

        // Jacobi fixpoint: wave 0 only; 3 cols/lane, 6 keep-words (r26).
        if (w == 0) {
            const int j0 = lane, j1 = lane + 64, j2 = lane + 128;
            const bool h0 = j0 < tm, h1 = j1 < tm, h2 = j2 < tm;
            unsigned int m00 = 0, m01 = 0, m02 = 0, m03 = 0, m04 = 0, m05 = 0;
            unsigned int m10 = 0, m11 = 0, m12 = 0, m13 = 0, m14 = 0, m15 = 0;
            unsigned int m20 = 0, m21 = 0, m22 = 0, m23 = 0, m24 = 0, m25 = 0;
            int ext0 = 0, ext1 = 0, ext2 = 0;
            if (h0) {
                m00 = s_supc[0 * NMS_TILE + j0];
                m01 = s_supc[1 * NMS_TILE + j0];
                m02 = s_supc[2 * NMS_TILE + j0];
                m03 = s_supc[3 * NMS_TILE + j0];
                m04 = s_supc[4 * NMS_TILE + j0];
                m05 = s_supc[5 * NMS_TILE + j0];
                ext0 = (int)s_keep[t0 + j0];
            }
            if (h1) {
                m10 = s_supc[0 * NMS_TILE + j1];
                m11 = s_supc[1 * NMS_TILE + j1];
                m12 = s_supc[2 * NMS_TILE + j1];
                m13 = s_supc[3 * NMS_TILE + j1];
                m14 = s_supc[4 * NMS_TILE + j1];
                m15 = s_supc[5 * NMS_TILE + j1];
                ext1 = (int)s_keep[t0 + j1];
            }
            if (h2) {
                m20 = s_supc[0 * NMS_TILE + j2];
                m21 = s_supc[1 * NMS_TILE + j2];
                m22 = s_supc[2 * NMS_TILE + j2];
                m23 = s_supc[3 * NMS_TILE + j2];
                m24 = s_supc[4 * NMS_TILE + j2];
                m25 = s_supc[5 * NMS_TILE + j2];
                ext2 = (int)s_keep[t0 + j2];
            }
            int alive0 = ext0, alive1 = ext1, alive2 = ext2;
            for (int round = 0; round < NMS_TILE; ++round) {
                unsigned long long A0b = __ballot(alive0 != 0);  // rows 0..63
                unsigned long long A1b = __ballot(alive1 != 0);  // rows 64..127
                unsigned long long A2b = __ballot(alive2 != 0);  // rows 128..191
                const unsigned int kw0 = (unsigned int)(A0b & 0xffffffffu);
                const unsigned int kw1 = (unsigned int)(A0b >> 32);
                const unsigned int kw2 = (unsigned int)(A1b & 0xffffffffu);
                const unsigned int kw3 = (unsigned int)(A1b >> 32);
                const unsigned int kw4 = (unsigned int)(A2b & 0xffffffffu);
                const unsigned int kw5 = (unsigned int)(A2b >> 32);
                int na0 = 0, na1 = 0, na2 = 0;
                if (ext0)
                    na0 = (((m00 & kw0) | (m01 & kw1) | (m02 & kw2) |
                            (m03 & kw3) | (m04 & kw4) | (m05 & kw5)) == 0u);
                if (ext1)
                    na1 = (((m10 & kw0) | (m11 & kw1) | (m12 & kw2) |
                            (m13 & kw3) | (m14 & kw4) | (m15 & kw5)) == 0u);
                if (ext2)
                    na2 = (((m20 & kw0) | (m21 & kw1) | (m22 & kw2) |
                            (m23 & kw3) | (m24 & kw4) | (m25 & kw5)) == 0u);
                const unsigned long long chg =
                    __ballot(na0 != alive0) | __ballot(na1 != alive1) |
                    __ballot(na2 != alive2);
                alive0 = na0; alive1 = na1; alive2 = na2;
                if (chg == 0ull) break;      // uniform within wave
            }
            if (h0) s_keep[t0 + j0] = (unsigned char)alive0;
            if (h1) s_keep[t0 + j1] = (unsigned char)alive1;
            if (h2) s_keep[t0 + j2] = (unsigned char)alive2;
        }
        __syncthreads();                     // keep state final for this tile
    }

    // ---- emit top-100 kept in sorted order -> ws: wave 0 only ----
    if (w == 0) {
        const int chunk = (M + 63) >> 6;     // contiguous slots per lane
        int lo = lane * chunk;
        int hi = lo + chunk; if (hi > M) hi = M;
        int cnt2 = 0;
        for (int jj = lo; jj < hi; ++jj) cnt2 += s_keep[jj];
        int inc2 = cnt2;
        for (int off = 1; off < 64; off <<= 1) {
            int n = __shfl_up(inc2, off, 64);
            if (lane >= off) inc2 += n;
        }
        int epos = inc2 - cnt2;              // exclusive prefix
        const int total = __shfl(inc2, 63, 64);

        float* osc = ws_scores + ((size_t)b * NMS_NUM_CLASSES + c) * NMS_MAX_PER_CLASS;
        float* obx = ws_boxes + (((size_t)b * NMS_NUM_CLASSES + c) * NMS_MAX_PER_CLASS) * 4;
        for (int jj = lo; jj < hi; ++jj) {
            if (s_keep[jj]) {
                if (epos < NMS_MAX_PER_CLASS) {
                    osc[epos] = s_sc[jj];
                    obx[epos * 4 + 0] = s_bx[jj * 4 + 0];
                    obx[epos * 4 + 1] = s_bx[jj * 4 + 1];
                    obx[epos * 4 + 2] = s_bx[jj * 4 + 2];
                    obx[epos * 4 + 3] = s_bx[jj * 4 + 3];
                }
                epos++;
            }
        }
        // pad positions [total, 100) with -1 (list stays sorted desc)
        for (int pp = lane; pp < NMS_MAX_PER_CLASS; pp += 64) {
            if (pp >= total) osc[pp] = -1.0f;
        }
    }

    // ---- last-block-done handoff (G16: device-scope fence + atomic) ----
    __syncthreads();                 // all per-class work done block-wide
    __threadfence();                 // release ws writes to device scope
    if (tid == 0) {
        int old = atomicAdd(&ws_count[b], 1);
        s_last = (old == NMS_NUM_CLASSES - 1);
    }
    __syncthreads();
    if (!s_last) return;
    __threadfence();                 // acquire: see other blocks' ws writes

    // =======================================================================
    // MERGE (one block per image): 16-way sorted-list top-100 via binsearch.
    // Per-class lists are sorted desc (pads -1). rank(slot c,i) =
    //   i  (own-class identity, r24-proven)
    // + sum over c'!=c of [count(sj > s) + (c'<c ? count(sj == s) : 0)]
    // which equals the r12 comparator summed over class block c'.
    // =======================================================================
    const float* isc = ws_scores + (size_t)b * NMS_NS;
    for (int t = tid; t < NMS_NS; t += 1024) s_scu[t] = isc[t];
    float* ob = out + (size_t)b * NMS_MAX_DET * 6;
    for (int t = tid; t < NMS_MAX_DET * 6; t += 1024) ob[t] = 0.0f;
    if (tid == 0) s_m = 0;           // reused as nvalid accumulator
    __syncthreads();                 // stage + zero-init complete

    for (int slot = tid; slot < NMS_NS; slot += 1024) {
        const int c2 = slot / NMS_MAX_PER_CLASS;
        const int i  = slot % NMS_MAX_PER_CLASS;
        const float s = s_scu[slot];
        int rk = i;
        for (int cc = 0; cc < NMS_NUM_CLASSES; ++cc) {
            if (cc == c2) continue;
            const int base = cc * NMS_MAX_PER_CLASS;
            // count_gt = first idx with value <= s  (list non-increasing)
            int lo = 0, hi = NMS_MAX_PER_CLASS;
            while (lo < hi) {
                int mid = (lo + hi) >> 1;
                if (s_scu[base + mid] > s) lo = mid + 1; else hi = mid;
            }
            int add = lo;
            if (cc < c2) {
                // ties: first idx with value < s, minus count_gt
                int lo2 = lo, hi2 = NMS_MAX_PER_CLASS;
                while (lo2 < hi2) {
                    int mid = (lo2 + hi2) >> 1;
                    if (s_scu[base + mid] >= s) lo2 = mid + 1; else hi2 = mid;
                }
                add += (lo2 - lo);
            }
            rk += add;
        }
        s_rk[slot] = rk;
    }
    __syncthreads();

    {
        int mycnt = 0;
        for (int slot = tid; slot < NMS_NS; slot += 1024) {
            const float s = s_scu[slot];
            if (s > NMS_SCORE_TH) {
                const int rk = s_rk[slot];
                if (rk < NMS_MAX_DET) {
                    const float* bx = ws_boxes + ((size_t)b * NMS_NS + slot) * 4;
                    float* row = ob + rk * 6;
                    row[0] = bx[0];
                    row[1] = bx[1];
                    row[2] = bx[2];
                    row[3] = bx[3];
                    row[4] = (float)(slot / NMS_MAX_PER_CLASS);
                    row[5] = s;
                    mycnt++;
                }
            }
        }
        if (mycnt) atomicAdd(&s_m, mycnt);
    }
    __syncthreads();
    if (tid == 0) out[(size_t)B * NMS_MAX_DET * 6 + b] = (float)s_m;
}

extern "C" void kernel_launch(void* const* d_in, const int* in_sizes, int n_in,
                              void* d_out, int out_size, void* d_ws, size_t ws_size,
                              hipStream_t stream) {
    const float* pred = (const float*)d_in[0];
    const int B = in_sizes[0] / (NMS_N * 6);
    if (B <= 0) return;
    float* out = (float*)d_out;

    float* ws_scores = (float*)d_ws;                         // B*1600 floats
    float* ws_boxes  = ws_scores + (size_t)B * NMS_NS;       // B*1600*4 floats
    int*   ws_count  = (int*)(ws_boxes + (size_t)B * NMS_NS * 4);  // B ints

    // zero the arrival counters (graph-capturable, ordered on stream)
    hipMemsetAsync(ws_count, 0, (size_t)B * sizeof(int), stream);

    nms_fused_kernel<<<dim3(B * NMS_NUM_CLASSES), dim3(1024), 0, stream>>>(
        pred, ws_scores, ws_boxes, ws_count, out, B);
}

// Round 9
// 75.935 us; speedup vs baseline: 1.4870x; 1.4870x over previous
//
#include <hip/hip_runtime.h>

#define NMS_NUM_CLASSES 16
#define NMS_N 2048
#define NMS_IOU_TH 0.5f
#define NMS_SCORE_TH 0.05f
#define NMS_MAX_DET 100
#define NMS_MAX_PER_CLASS 100
#define NMS_NS (NMS_NUM_CLASSES * NMS_MAX_PER_CLASS)   // 1600
#define NMS_TILE 192                 // 3 cols/lane; P(M>192) ~ 1e-10

// SESSION PITFALLS (r1-r28):
//  * float4 casts on __shared__ float -> ds_read_b128 misalignment fault.
//  * u64 LDS arrays / LDS pointer casts correlated with container deaths.
//    ONLY declared __shared__ float/uint/uchar arrays, scalar access.
//  * Serial NMS chains cost 45-65 us at M~122 -> Jacobi fixpoint (r15).
//  * Fusion via grid.sync REGRESSED (+5us). r27: last-block-done fusion
//    (threadfence + device atomic) REGRESSED +36us: per-block device-scope
//    fences (L2 wb/inv across 8 XCDs) cost ~44us vs ~1.4us dispatch gap.
//    DISPATCH BOUNDARY IS THE CHEAP CROSS-CLASS SYNC. Also: binsearch rank
//    = 105-step DEPENDENT chain, slower than 100 pipelined linear loads.
//  * r20: barrier removal at 16 waves: NO change. r21/r22: wave-count law,
//    16 waves best. r24: full-M chains regress; r25: chain 16 vs 32 null.
//  * r26: TILE=192 single-tile for max-M blocks: 95.7 -> 76.4 (k1 ~38->~19).
//    Duration = MAX over blocks; the Binomial tail block ran a 2nd tile.
//  * r28 (this round): exact r26 revert (proven 76.4). Remaining budget:
//    fill 40 (harness) + k1 ~19 + k2 ~8 + gaps ~9. Rejected by analysis:
//    k2 pad-skip (no pads: ~2 suppressions/class), chunk early-out (foreign
//    tops ~0.99), LDS shrink (block-count-limited, 64 blocks < 256 CUs).

__device__ __forceinline__ int nms_cmp(float sj, int ij, float sq, int iq) {
    // EXACT r12 comparator semantics, bitwise (no short-circuit branches)
    return ((int)(sj > sq)) | (((int)(sj == sq)) & ((int)(ij < iq)));
}

// ---------------------------------------------------------------------------
// Kernel 1: one block per (image, class), 1024 threads (16 waves).
// ---------------------------------------------------------------------------
__global__ __launch_bounds__(1024) void nms_per_class_kernel(
    const float* __restrict__ pred,   // [B, N, 6] x1,y1,x2,y2,cls,score
    float* __restrict__ ws_scores,    // [B, 1600]
    float* __restrict__ ws_boxes,     // [B, 1600, 4]
    float* __restrict__ out,          // [B*600] rows + [B] nvalid
    int B)
{
    const int b = blockIdx.x / NMS_NUM_CLASSES;
    const int c = blockIdx.x % NMS_NUM_CLASSES;
    const float* p = pred + (size_t)b * NMS_N * 6;
    const int tid = threadIdx.x;
    const int lane = tid & 63;
    const int w = tid >> 6;                  // wave id 0..15

    // zero-init output for this image (k2 is a later dispatch on the stream)
    if (c == 0) {
        float* ob = out + (size_t)b * NMS_MAX_DET * 6;
        for (int t = tid; t < NMS_MAX_DET * 6; t += 1024) ob[t] = 0.0f;
        if (tid == 0) out[(size_t)B * NMS_MAX_DET * 6 + b] = 0.0f;
    }

    __shared__ float s_scu[NMS_N];           // unsorted scores
    __shared__ int   s_ixu[NMS_N];           // unsorted original indices
    __shared__ float s_bxu[NMS_N * 4];       // unsorted boxes
    __shared__ int   s_rk[NMS_N];            // rank accumulators
    __shared__ float s_sc[NMS_N];            // sorted scores
    __shared__ float s_bx[NMS_N * 4];        // sorted boxes
    __shared__ unsigned char s_keep[NMS_N];
    __shared__ unsigned int s_supc[6 * NMS_TILE];  // [window32][col] u32 masks
    __shared__ int s_m;

    if (tid == 0) s_m = 0;
    __syncthreads();

    // ---- compact: wave-aggregated (r20/r23-proven), s_rk zero fused ----
    const float2* p2 = (const float2*)p;     // row i = p2[3i], p2[3i+1], p2[3i+2]
    for (int i = tid; i < NMS_N; i += 1024) { // uniform trips
        s_rk[i] = 0;
        float2 v0 = p2[i * 3 + 0];           // x1, y1
        float2 v1 = p2[i * 3 + 1];           // x2, y2
        float2 v2 = p2[i * 3 + 2];           // cls, score
        const bool ok = ((int)v2.x == c) && (v2.y > NMS_SCORE_TH);
        unsigned long long mask = __ballot(ok);
        int base = 0;
        if (lane == 0) {
            int cnt = __popcll(mask);
            if (cnt) base = atomicAdd(&s_m, cnt);
        }
        base = __shfl(base, 0, 64);
        if (ok) {
            int pos = base + __popcll(mask & ((1ull << lane) - 1ull));
            s_scu[pos] = v2.y;
            s_ixu[pos] = i;
            s_bxu[pos * 4 + 0] = v0.x;
            s_bxu[pos * 4 + 1] = v0.y;
            s_bxu[pos * 4 + 2] = v1.x;
            s_bxu[pos * 4 + 3] = v1.y;
        }
    }
    __syncthreads();
    const int M = s_m;

    // ---- rank: (q, 32-chunk) tasks (r23-proven), branchless 4x-unrolled.
    //      M~122 -> 488 tasks, one per thread, chain = 32 cmps ----
    {
        const int nch = (M + 31) >> 5;
        const int ntask = M * nch;
        for (int task = tid; task < ntask; task += 1024) {
            const int q = task % M;          // consecutive tids -> distinct q
            const int ch = task / M;
            const float sq = s_scu[q];
            const int   iq = s_ixu[q];
            const int j0 = ch << 5;
            int jend = j0 + 32; if (jend > M) jend = M;
            int r0 = 0, r1 = 0, r2 = 0, r3 = 0;
            int j = j0;
            for (; j + 4 <= jend; j += 4) {
                float sa = s_scu[j + 0], sb = s_scu[j + 1];
                float sc2 = s_scu[j + 2], sd = s_scu[j + 3];
                int ia = s_ixu[j + 0], ib = s_ixu[j + 1];
                int ic = s_ixu[j + 2], id = s_ixu[j + 3];
                r0 += nms_cmp(sa, ia, sq, iq);
                r1 += nms_cmp(sb, ib, sq, iq);
                r2 += nms_cmp(sc2, ic, sq, iq);
                r3 += nms_cmp(sd, id, sq, iq);
            }
            for (; j < jend; ++j)
                r0 += nms_cmp(s_scu[j], s_ixu[j], sq, iq);
            const int rk = (r0 + r1) + (r2 + r3);
            if (rk) atomicAdd(&s_rk[q], rk);
        }
    }
    __syncthreads();
    for (int q = tid; q < M; q += 1024) {
        int rk = s_rk[q];
        s_sc[rk] = s_scu[q];
        s_bx[rk * 4 + 0] = s_bxu[q * 4 + 0];
        s_bx[rk * 4 + 1] = s_bxu[q * 4 + 1];
        s_bx[rk * 4 + 2] = s_bxu[q * 4 + 2];
        s_bx[rk * 4 + 3] = s_bxu[q * 4 + 3];
        s_keep[rk] = 1;
    }
    __syncthreads();

    // ---- tiled NMS (one tile for all realistic M; loop = M>192 fallback) ----
    for (int t0 = 0; t0 < M; t0 += NMS_TILE) {
        const int tm = (M - t0 < NMS_TILE) ? (M - t0) : NMS_TILE;

        // A0 fallback: never executes for M <= 192 (the benched regime).
        if (t0 > 0) {
            for (int jj = tid; jj < tm; jj += 1024) {
                const int gj = t0 + jj;
                float jx1 = s_bx[gj * 4 + 0], jy1 = s_bx[gj * 4 + 1];
                float jx2 = s_bx[gj * 4 + 2], jy2 = s_bx[gj * 4 + 3];
                float aj = (jy2 - jy1) * (jx2 - jx1);
                int dead = 0;
                for (int i = 0; i < t0 && !dead; ++i) {
                    if (!s_keep[i]) continue;
                    float ix1 = s_bx[i * 4 + 0], iy1 = s_bx[i * 4 + 1];
                    float ix2 = s_bx[i * 4 + 2], iy2 = s_bx[i * 4 + 3];
                    float ai = (iy2 - iy1) * (ix2 - ix1);
                    float ih = fminf(iy2, jy2) - fmaxf(iy1, jy1);
                    ih = fmaxf(ih, 0.0f);
                    float iw = fminf(ix2, jx2) - fmaxf(ix1, jx1);
                    iw = fmaxf(iw, 0.0f);
                    float inter = ih * iw;
                    float uni = ai + aj - inter;
                    float iou = (inter > 0.0f) ? inter / fmaxf(uni, 1e-08f) : 0.0f;
                    dead = iou > NMS_IOU_TH;
                }
                if (dead) s_keep[gj] = 0;
            }
            __syncthreads();
        }

        // supc: (wi, j) tasks over SIX 32-row windows; u32 masks.
        // M~122 -> 6*122 = 732 tasks, one per thread, chain <= 32 IoU.
        for (int idx = tid; idx < 6 * tm; idx += 1024) {
            const int wi = idx / tm;
            const int jj = idx % tm;
            const int ibase = wi << 5;
            unsigned int m0 = 0, m1 = 0, m2 = 0, m3 = 0;
            int iend = jj - ibase;           // only i < j
            if (iend > 32) iend = 32;
            if (iend > 0) {
                const int gj = t0 + jj;
                float jx1 = s_bx[gj * 4 + 0], jy1 = s_bx[gj * 4 + 1];
                float jx2 = s_bx[gj * 4 + 2], jy2 = s_bx[gj * 4 + 3];
                float aj = (jy2 - jy1) * (jx2 - jx1);
                int bb = 0;
                for (; bb + 4 <= iend; bb += 4) {
#define NMS_SUP1(K, MK)                                                        \
                    {                                                          \
                        const int gi = t0 + ibase + bb + (K);                  \
                        float ix1 = s_bx[gi * 4 + 0], iy1 = s_bx[gi * 4 + 1];  \
                        float ix2 = s_bx[gi * 4 + 2], iy2 = s_bx[gi * 4 + 3];  \
                        float ai = (iy2 - iy1) * (ix2 - ix1);                  \
                        float ih = fminf(iy2, jy2) - fmaxf(iy1, jy1);          \
                        ih = fmaxf(ih, 0.0f);                                  \
                        float iw = fminf(ix2, jx2) - fmaxf(ix1, jx1);          \
                        iw = fmaxf(iw, 0.0f);                                  \
                        float inter = ih * iw;                                 \
                        float uni = ai + aj - inter;                           \
                        float iou = (inter > 0.0f) ? inter / fmaxf(uni, 1e-08f) : 0.0f; \
                        MK |= (iou > NMS_IOU_TH) ? (1u << (bb + (K))) : 0u;    \
                    }
                    NMS_SUP1(0, m0)
                    NMS_SUP1(1, m1)
                    NMS_SUP1(2, m2)
                    NMS_SUP1(3, m3)
                }
                for (; bb < iend; ++bb) {
                    const int gi = t0 + ibase + bb;
                    float ix1 = s_bx[gi * 4 + 0], iy1 = s_bx[gi * 4 + 1];
                    float ix2 = s_bx[gi * 4 + 2], iy2 = s_bx[gi * 4 + 3];
                    float ai = (iy2 - iy1) * (ix2 - ix1);
                    float ih = fminf(iy2, jy2) - fmaxf(iy1, jy1);
                    ih = fmaxf(ih, 0.0f);
                    float iw = fminf(ix2, jx2) - fmaxf(ix1, jx1);
                    iw = fmaxf(iw, 0.0f);
                    float inter = ih * iw;
                    float uni = ai + aj - inter;
                    float iou = (inter > 0.0f) ? inter / fmaxf(uni, 1e-08f) : 0.0f;
                    m0 |= (iou > NMS_IOU_TH) ? (1u << bb) : 0u;
                }
#undef NMS_SUP1
            }
            s_supc[wi * NMS_TILE + jj] = (m0 | m1) | (m2 | m3);
        }
        __syncthreads();                     // supc complete

        // Jacobi fixpoint: wave 0 only, register/ballot-resident.
        // 3 columns/lane (lane, +64, +128); 6 keep-words from 3 ballots.
        if (w == 0) {
            const int j0 = lane, j1 = lane + 64, j2 = lane + 128;
            const bool h0 = j0 < tm, h1 = j1 < tm, h2 = j2 < tm;
            unsigned int m00 = 0, m01 = 0, m02 = 0, m03 = 0, m04 = 0, m05 = 0;
            unsigned int m10 = 0, m11 = 0, m12 = 0, m13 = 0, m14 = 0, m15 = 0;
            unsigned int m20 = 0, m21 = 0, m22 = 0, m23 = 0, m24 = 0, m25 = 0;
            int ext0 = 0, ext1 = 0, ext2 = 0;
            if (h0) {
                m00 = s_supc[0 * NMS_TILE + j0];
                m01 = s_supc[1 * NMS_TILE + j0];
                m02 = s_supc[2 * NMS_TILE + j0];
                m03 = s_supc[3 * NMS_TILE + j0];
                m04 = s_supc[4 * NMS_TILE + j0];
                m05 = s_supc[5 * NMS_TILE + j0];
                ext0 = (int)s_keep[t0 + j0];
            }
            if (h1) {
                m10 = s_supc[0 * NMS_TILE + j1];
                m11 = s_supc[1 * NMS_TILE + j1];
                m12 = s_supc[2 * NMS_TILE + j1];
                m13 = s_supc[3 * NMS_TILE + j1];
                m14 = s_supc[4 * NMS_TILE + j1];
                m15 = s_supc[5 * NMS_TILE + j1];
                ext1 = (int)s_keep[t0 + j1];
            }
            if (h2) {
                m20 = s_supc[0 * NMS_TILE + j2];
                m21 = s_supc[1 * NMS_TILE + j2];
                m22 = s_supc[2 * NMS_TILE + j2];
                m23 = s_supc[3 * NMS_TILE + j2];
                m24 = s_supc[4 * NMS_TILE + j2];
                m25 = s_supc[5 * NMS_TILE + j2];
                ext2 = (int)s_keep[t0 + j2];
            }
            int alive0 = ext0, alive1 = ext1, alive2 = ext2;
            for (int round = 0; round < NMS_TILE; ++round) {
                unsigned long long A0b = __ballot(alive0 != 0);  // rows 0..63
                unsigned long long A1b = __ballot(alive1 != 0);  // rows 64..127
                unsigned long long A2b = __ballot(alive2 != 0);  // rows 128..191
                const unsigned int kw0 = (unsigned int)(A0b & 0xffffffffu);
                const unsigned int kw1 = (unsigned int)(A0b >> 32);
                const unsigned int kw2 = (unsigned int)(A1b & 0xffffffffu);
                const unsigned int kw3 = (unsigned int)(A1b >> 32);
                const unsigned int kw4 = (unsigned int)(A2b & 0xffffffffu);
                const unsigned int kw5 = (unsigned int)(A2b >> 32);
                int na0 = 0, na1 = 0, na2 = 0;
                if (ext0)
                    na0 = (((m00 & kw0) | (m01 & kw1) | (m02 & kw2) |
                            (m03 & kw3) | (m04 & kw4) | (m05 & kw5)) == 0u);
                if (ext1)
                    na1 = (((m10 & kw0) | (m11 & kw1) | (m12 & kw2) |
                            (m13 & kw3) | (m14 & kw4) | (m15 & kw5)) == 0u);
                if (ext2)
                    na2 = (((m20 & kw0) | (m21 & kw1) | (m22 & kw2) |
                            (m23 & kw3) | (m24 & kw4) | (m25 & kw5)) == 0u);
                const unsigned long long chg =
                    __ballot(na0 != alive0) | __ballot(na1 != alive1) |
                    __ballot(na2 != alive2);
                alive0 = na0; alive1 = na1; alive2 = na2;
                if (chg == 0ull) break;      // uniform within wave
            }
            if (h0) s_keep[t0 + j0] = (unsigned char)alive0;
            if (h1) s_keep[t0 + j1] = (unsigned char)alive1;
            if (h2) s_keep[t0 + j2] = (unsigned char)alive2;
        }
        __syncthreads();                     // keep state final for this tile
    }

    // ---- emit top-100 kept in sorted order: wave 0 only (r21-r26-proven) ----
    if (w == 0) {
        const int chunk = (M + 63) >> 6;     // contiguous slots per lane
        int lo = lane * chunk;
        int hi = lo + chunk; if (hi > M) hi = M;
        int cnt2 = 0;
        for (int jj = lo; jj < hi; ++jj) cnt2 += s_keep[jj];
        int inc2 = cnt2;
        for (int off = 1; off < 64; off <<= 1) {
            int n = __shfl_up(inc2, off, 64);
            if (lane >= off) inc2 += n;
        }
        int epos = inc2 - cnt2;              // exclusive prefix
        const int total = __shfl(inc2, 63, 64);

        float* osc = ws_scores + ((size_t)b * NMS_NUM_CLASSES + c) * NMS_MAX_PER_CLASS;
        float* obx = ws_boxes + (((size_t)b * NMS_NUM_CLASSES + c) * NMS_MAX_PER_CLASS) * 4;
        for (int jj = lo; jj < hi; ++jj) {
            if (s_keep[jj]) {
                if (epos < NMS_MAX_PER_CLASS) {
                    osc[epos] = s_sc[jj];
                    obx[epos * 4 + 0] = s_bx[jj * 4 + 0];
                    obx[epos * 4 + 1] = s_bx[jj * 4 + 1];
                    obx[epos * 4 + 2] = s_bx[jj * 4 + 2];
                    obx[epos * 4 + 3] = s_bx[jj * 4 + 3];
                }
                epos++;
            }
        }
        // pad positions [total, 100) with -1
        for (int pp = lane; pp < NMS_MAX_PER_CLASS; pp += 64) {
            if (pp >= total) osc[pp] = -1.0f;
        }
    }
}

// ---------------------------------------------------------------------------
// Kernel 2: one block per (image, class), 1024 threads. Rank semantics
// identical to r12/r23 (same comparator + tie-break). r24/r25-proven:
// own-class chunk contribution of slot i is EXACTLY i (sorted desc; j<i
// ties count via j<flat, j>i ties don't) -> s_rank init = i and 15 foreign
// chunks; each thread's two tasks interleaved for ILP.
// ---------------------------------------------------------------------------
__global__ __launch_bounds__(1024) void nms_topk_kernel(
    const float* __restrict__ ws_scores,   // [B, 1600]
    const float* __restrict__ ws_boxes,    // [B, 1600, 4]
    float* __restrict__ out,               // [B*600] rows + [B] nvalid
    int B)
{
    const int b = blockIdx.x / NMS_NUM_CLASSES;
    const int c = blockIdx.x % NMS_NUM_CLASSES;
    const int cbase = c * NMS_MAX_PER_CLASS;
    __shared__ float s_sc[NMS_NS];
    __shared__ int s_rank[NMS_MAX_PER_CLASS];

    const float* isc = ws_scores + (size_t)b * NMS_NS;
    for (int t = threadIdx.x; t < NMS_NS; t += blockDim.x) s_sc[t] = isc[t];
    if (threadIdx.x < NMS_MAX_PER_CLASS) s_rank[threadIdx.x] = threadIdx.x;
    __syncthreads();

    // 1500 tasks = 100 slots x 15 foreign chunks; thread handles tasks
    // tid and tid+1024 (if any) INTERLEAVED (independent load streams).
    {
        const int tA = threadIdx.x;              // 1024 <= 1500, always valid
        const int tB = threadIdx.x + 1024;
        const bool hB = tB < NMS_MAX_PER_CLASS * 15;
        const int slotA = tA % NMS_MAX_PER_CLASS;
        const int chA0 = tA / NMS_MAX_PER_CLASS;
        const int chA = chA0 + (chA0 >= c ? 1 : 0);      // skip own chunk
        const int slotB = hB ? (tB % NMS_MAX_PER_CLASS) : slotA;
        const int chB0 = hB ? (tB / NMS_MAX_PER_CLASS) : chA0;
        const int chB = chB0 + (chB0 >= c ? 1 : 0);
        const int flatA = cbase + slotA;
        const int flatB = cbase + slotB;
        const float sA = s_sc[flatA];
        const float sB = s_sc[flatB];
        const int jA0 = chA * 100;
        const int jB0 = chB * 100;
        int a0 = 0, a1 = 0, a2 = 0, a3 = 0;
        int b0 = 0, b1 = 0, b2 = 0, b3 = 0;
        for (int k = 0; k < 100; k += 4) {
            const int ja = jA0 + k, jb = jB0 + k;
            float va0 = s_sc[ja + 0], va1 = s_sc[ja + 1];
            float va2 = s_sc[ja + 2], va3 = s_sc[ja + 3];
            float vb0 = s_sc[jb + 0], vb1 = s_sc[jb + 1];
            float vb2 = s_sc[jb + 2], vb3 = s_sc[jb + 3];
            a0 += ((int)(va0 > sA)) | (((int)(va0 == sA)) & ((int)(ja + 0 < flatA)));
            a1 += ((int)(va1 > sA)) | (((int)(va1 == sA)) & ((int)(ja + 1 < flatA)));
            a2 += ((int)(va2 > sA)) | (((int)(va2 == sA)) & ((int)(ja + 2 < flatA)));
            a3 += ((int)(va3 > sA)) | (((int)(va3 == sA)) & ((int)(ja + 3 < flatA)));
            b0 += ((int)(vb0 > sB)) | (((int)(vb0 == sB)) & ((int)(jb + 0 < flatB)));
            b1 += ((int)(vb1 > sB)) | (((int)(vb1 == sB)) & ((int)(jb + 1 < flatB)));
            b2 += ((int)(vb2 > sB)) | (((int)(vb2 == sB)) & ((int)(jb + 2 < flatB)));
            b3 += ((int)(vb3 > sB)) | (((int)(vb3 == sB)) & ((int)(jb + 3 < flatB)));
        }
        const int rkA = (a0 + a1) + (a2 + a3);
        const int rkB = (b0 + b1) + (b2 + b3);
        if (rkA) atomicAdd(&s_rank[slotA], rkA);
        if (hB && rkB) atomicAdd(&s_rank[slotB], rkB);
    }
    __syncthreads();

    int is_top = 0;
    const int t = threadIdx.x;
    if (t < NMS_MAX_PER_CLASS) {
        const int slot = cbase + t;
        float s = s_sc[slot];
        if (s > NMS_SCORE_TH) {
            int rk = s_rank[t];
            if (rk < NMS_MAX_DET) {
                const float* bx = ws_boxes + ((size_t)b * NMS_NS + slot) * 4;
                float* row = out + (size_t)b * NMS_MAX_DET * 6 + rk * 6;
                row[0] = bx[0];
                row[1] = bx[1];
                row[2] = bx[2];
                row[3] = bx[3];
                row[4] = (float)c;
                row[5] = s;
                is_top = 1;
            }
        }
    }
    unsigned long long m = __ballot(is_top);
    if ((threadIdx.x & 63) == 0) {
        float cnt = (float)__popcll(m);
        if (cnt > 0.0f)
            atomicAdd(&out[(size_t)B * NMS_MAX_DET * 6 + b], cnt);
    }
}

extern "C" void kernel_launch(void* const* d_in, const int* in_sizes, int n_in,
                              void* d_out, int out_size, void* d_ws, size_t ws_size,
                              hipStream_t stream) {
    const float* pred = (const float*)d_in[0];
    const int B = in_sizes[0] / (NMS_N * 6);
    if (B <= 0) return;
    float* out = (float*)d_out;

    float* ws_scores = (float*)d_ws;
    float* ws_boxes = ws_scores + (size_t)B * NMS_NS;

    nms_per_class_kernel<<<dim3(B * NMS_NUM_CLASSES), dim3(1024), 0, stream>>>(
        pred, ws_scores, ws_boxes, out, B);
    nms_topk_kernel<<<dim3(B * NMS_NUM_CLASSES), dim3(1024), 0, stream>>>(
        ws_scores, ws_boxes, out, B);
}